// Round 13
// baseline (713.512 us; speedup 1.0000x reference)
//
#include <hip/hip_runtime.h>
#include <hip/hip_bf16.h>

#define EPS 1e-5f

// ---------------------------------------------------------------- stats ----
__global__ __launch_bounds__(256) void stats_kernel(
    const float* __restrict__ buf, float* __restrict__ mean,
    float* __restrict__ rstd) {
  int bc = blockIdx.x;
  const float* ch = buf + (size_t)bc * 32768;
  float s = 0.f, ss = 0.f;
  for (int i = threadIdx.x; i < 32768; i += 256) {
    float v = ch[i];
    s += v; ss += v * v;
  }
  for (int o = 32; o; o >>= 1) {
    s += __shfl_down(s, o);
    ss += __shfl_down(ss, o);
  }
  __shared__ float sb[4], ssb[4];
  int wid = threadIdx.x >> 6, lane = threadIdx.x & 63;
  if (lane == 0) { sb[wid] = s; ssb[wid] = ss; }
  __syncthreads();
  if (threadIdx.x == 0) {
    float S = 0.f, SS = 0.f;
    for (int w = 0; w < 4; ++w) { S += sb[w]; SS += ssb[w]; }
    float m = S * (1.f / 32768.f);
    float var = SS * (1.f / 32768.f) - m * m;
    mean[bc] = m;
    rstd[bc] = rsqrtf(var + EPS);
  }
}

// ------------------------------------------------------------------- SE ----
__global__ void se_kernel(const float* __restrict__ mean_x,
                          const float* __restrict__ w1, const float* __restrict__ b1,
                          const float* __restrict__ w2, const float* __restrict__ b2,
                          float* __restrict__ dw) {
  __shared__ float hbuf[32];
  int t = threadIdx.x;
  if (t < 32) {
    int b = t >> 4, j = t & 15;
    float a = b1[j];
    for (int c = 0; c < 64; ++c) a += mean_x[b * 64 + c] * w1[j * 64 + c];
    hbuf[t] = a >= 0.f ? a : 0.2f * a;
  }
  __syncthreads();
  if (t < 2) {
    int b = t;
    float l0 = b2[0], l1 = b2[1];
    for (int j = 0; j < 16; ++j) {
      float h = hbuf[b * 16 + j];
      l0 += h * w2[j];
      l1 += h * w2[16 + j];
    }
    float m = fmaxf(l0, l1);
    float e0 = __expf(l0 - m), e1 = __expf(l1 - m);
    float inv = 1.f / (e0 + e1);
    dw[b * 2 + 0] = e0 * inv;
    dw[b * 2 + 1] = e1 * inv;
  }
}

// --------------------------------------------- transpose w_def -> [k][i][o]
__global__ __launch_bounds__(256) void prep_wdef(const float* __restrict__ w_def,
                                                 float* __restrict__ wTd) {
  int idx = blockIdx.x * 256 + threadIdx.x;  // 27*32*32 = 27648
  if (idx < 27648) {
    int o = idx & 31, rest = idx >> 5;
    int i = rest & 31, k = rest >> 5;
    wTd[idx] = w_def[(size_t)(o * 32 + i) * 27 + k];
  }
}

// ------------------------------- transpose w_off [81,32,27] -> [27][32][81]
__global__ __launch_bounds__(256) void prep_woff(const float* __restrict__ w_off,
                                                 float* __restrict__ wT) {
  int idx = blockIdx.x * 256 + threadIdx.x;  // 27*32*81 = 69984
  if (idx < 69984) {
    int o = idx % 81, rest = idx / 81;
    int i = rest & 31, t = rest >> 5;
    wT[idx] = w_off[(size_t)(o * 32 + i) * 27 + t];
  }
}

// -------------------------------- transpose w_na [32,32,27] -> [27][32][32]
__global__ __launch_bounds__(256) void prep_wna(const float* __restrict__ w_na,
                                                float* __restrict__ wT) {
  int idx = blockIdx.x * 256 + threadIdx.x;  // 27*32*32 = 27648
  if (idx < 27648) {
    int o = idx & 31, rest = idx >> 5;
    int i = rest & 31, t = rest >> 5;
    wT[idx] = w_na[(size_t)(o * 32 + i) * 27 + t];
  }
}

// ------------------- fused inorm+lrelu+1x1 (64->32), o-split x4 -----------
__global__ __launch_bounds__(256) void first_conv_kernel(
    const float* __restrict__ x, const float* __restrict__ w,   // [32,64]
    const float* __restrict__ bias,
    const float* __restrict__ meanp, const float* __restrict__ rstdp,
    float* __restrict__ f_cp) {
  int og = blockIdx.x >> 8;
  int chunk = blockIdx.x & 255;
  int vg = chunk * 256 + threadIdx.x;
  int b = vg >> 15, p = vg & 32767;
  float acc[8];
#pragma unroll
  for (int o = 0; o < 8; ++o) acc[o] = 0.f;
  const float* xb = x + ((size_t)b * 64) * 32768;
  const float* wg = w + (size_t)og * 8 * 64;
  for (int i = 0; i < 64; ++i) {
    float v = xb[(size_t)i * 32768 + p];
    float m = meanp[b * 64 + i], r = rstdp[b * 64 + i];
    v = (v - m) * r;
    v = v >= 0.f ? v : 0.2f * v;
#pragma unroll
    for (int o = 0; o < 8; ++o) acc[o] = fmaf(wg[o * 64 + i], v, acc[o]);
  }
#pragma unroll
  for (int o = 0; o < 8; ++o)
    f_cp[((size_t)b * 32 + og * 8 + o) * 32768 + p] = acc[o] + bias[og * 8 + o];
}

// ------------------------- f_norm = lrelu(inorm(f)) elementwise -----------
__global__ __launch_bounds__(256) void norm_f_kernel(
    const float* __restrict__ f_cp, const float* __restrict__ meanp,
    const float* __restrict__ rstdp, float* __restrict__ f_norm) {
  int i4 = blockIdx.x * 256 + threadIdx.x;   // 524288 float4 groups
  int bc = (i4 * 4) >> 15;
  float m = meanp[bc], r = rstdp[bc];
  float4 v = ((const float4*)f_cp)[i4];
  float4 o;
  o.x = (v.x - m) * r; o.x = o.x >= 0.f ? o.x : 0.2f * o.x;
  o.y = (v.y - m) * r; o.y = o.y >= 0.f ? o.y : 0.2f * o.y;
  o.z = (v.z - m) * r; o.z = o.z >= 0.f ? o.z : 0.2f * o.z;
  o.w = (v.w - m) * r; o.w = o.w >= 0.f ? o.w : 0.2f * o.w;
  ((float4*)f_norm)[i4] = o;
}

// ---------------- implicit-GEMM direct 3x3x3 conv (no LDS, no barriers) ---
template <int OCG, int OCT, bool REFLECT>
__global__ __launch_bounds__(256) void conv3_direct_kernel(
    const float* __restrict__ in,    // [B,32,32768]
    const float* __restrict__ wT,    // [27,32,OCT]
    const float* __restrict__ bias,  // [OCT]
    float* __restrict__ out) {       // [B,OCT,32768]
  int og = blockIdx.x >> 8;
  int chunk = blockIdx.x & 255;
  int vg = chunk * 256 + threadIdx.x;
  int b = vg >> 15, p = vg & 32767;
  int z = p >> 10, y = (p >> 5) & 31, x = p & 31;
  const float* base = in + ((size_t)b * 32) * 32768;

  float acc[OCG];
#pragma unroll
  for (int o = 0; o < OCG; ++o) acc[o] = 0.f;

  for (int t = 0; t < 27; ++t) {
    int dz = t / 9, dy = (t / 3) % 3, dx = t % 3;
    int zz = z + dz - 1, yy = y + dy - 1, xx = x + dx - 1;
    bool valid = true;
    if (REFLECT) {
      zz = zz < 0 ? -zz : (zz > 31 ? 62 - zz : zz);
      yy = yy < 0 ? -yy : (yy > 31 ? 62 - yy : yy);
      xx = xx < 0 ? -xx : (xx > 31 ? 62 - xx : xx);
    } else {
      valid = (unsigned)zz < 32u && (unsigned)yy < 32u && (unsigned)xx < 32u;
      if (!valid) { zz = 0; yy = 0; xx = 0; }
    }
    int off = (zz * 32 + yy) * 32 + xx;
    const float* cptr = base + off;
    const float* wt = wT + (size_t)t * 32 * OCT + og * OCG;  // wave-uniform
#pragma unroll 4
    for (int i = 0; i < 32; ++i) {
      float v = cptr[(size_t)i << 15];
      if (!REFLECT) v = valid ? v : 0.f;
#pragma unroll
      for (int o = 0; o < OCG; ++o)
        acc[o] = fmaf(wt[i * OCT + o], v, acc[o]);
    }
  }
  float* op = out + ((size_t)b * OCT + og * OCG) * 32768 + p;
#pragma unroll
  for (int o = 0; o < OCG; ++o)
    op[(size_t)o * 32768] = acc[o] + bias[og * OCG + o];
}

// --------------------------------------------------------------- deform ----
// v4: channel-planar gather from f_cp. Per tap: 8 corner (addr, masked-wt)
// computed once; inner i-loop reads f_cp[i][addr_c] -- a wave's lanes are
// CONSECUTIVE positions, so each load instruction touches ~4-6 cache lines
// (vs 64 with the [pos][c] float4 gather => 8x less L1 line traffic, the
// measured bottleneck). Matmul stays wave-uniform-SGPR, i-outer/o-inner.
__global__ __launch_bounds__(256) void deform_kernel(
    const float* __restrict__ f_cp,  // [B,32,32768]
    const float* __restrict__ offs,  // [B,81,32768]
    const float* __restrict__ wTd,   // [27,32,32] (k,i,o)
    float* __restrict__ part) {      // [3,B,32,32768]
  int bid = blockIdx.x;
  int kg = bid >> 8;                 // 0..2
  int tile = bid & 255;
  int vg = tile * 256 + threadIdx.x;
  int b = vg >> 15, p = vg & 32767;
  int z = p >> 10, y = (p >> 5) & 31, x = p & 31;
  const float* fb = f_cp + ((size_t)b * 32) * 32768;
  const float* ob = offs + (((size_t)b * 81) << 15);
  int kz = kg - 1;

  float acc[32];
#pragma unroll
  for (int o = 0; o < 32; ++o) acc[o] = 0.f;

  for (int kk = 0; kk < 9; ++kk) {
    int k = kg * 9 + kk;
    int ky = kk / 3 - 1, kx = kk % 3 - 1;

    float oz = ob[(size_t)(k * 3 + 0) * 32768 + p];
    float oy = ob[(size_t)(k * 3 + 1) * 32768 + p];
    float ox = ob[(size_t)(k * 3 + 2) * 32768 + p];
    float pz = (float)(z + kz) + oz;
    float py = (float)(y + ky) + oy;
    float px = (float)(x + kx) + ox;
    float fz = floorf(pz), fy = floorf(py), fxx = floorf(px);
    int iz0 = (int)fz, iy0 = (int)fy, ix0 = (int)fxx;
    float rz = pz - fz, ry = py - fy, rx = px - fxx;

    int addr[8];
    float wtm[8];
#pragma unroll
    for (int corner = 0; corner < 8; ++corner) {
      int dz = corner >> 2, dy = (corner >> 1) & 1, dxx = corner & 1;
      int iz = iz0 + dz, iy = iy0 + dy, ix = ix0 + dxx;
      bool okb = (unsigned)iz < 32u && (unsigned)iy < 32u && (unsigned)ix < 32u;
      float wt = (dz ? rz : 1.f - rz) * (dy ? ry : 1.f - ry) *
                 (dxx ? rx : 1.f - rx);
      addr[corner] = okb ? (iz * 32 + iy) * 32 + ix : 0;
      wtm[corner] = okb ? wt : 0.f;
    }

#pragma unroll 2
    for (int i = 0; i < 32; ++i) {
      const float* ci = fb + ((size_t)i << 15);
      float v = 0.f;
#pragma unroll
      for (int c = 0; c < 8; ++c) v = fmaf(wtm[c], ci[addr[c]], v);
      const float* wr = wTd + ((size_t)k * 32 + i) * 32;  // wave-uniform
#pragma unroll
      for (int o = 0; o < 32; ++o) acc[o] = fmaf(wr[o], v, acc[o]);
    }
  }
  float* obp = part + (((size_t)kg * 2 + b) * 32) * 32768 + p;
#pragma unroll
  for (int o = 0; o < 32; ++o) obp[(size_t)o * 32768] = acc[o];
}

// ------------------- combine (3 partials + alpha) + partial stats ---------
__global__ __launch_bounds__(256) void combine_kernel(
    const float* __restrict__ part, const float* __restrict__ alpha,
    const float* __restrict__ dw, float* __restrict__ comb,
    float* __restrict__ partial) {   // [256][2]
  int blk = blockIdx.x;              // 64 bc x 4 quarters
  int bc = blk >> 2, qt = blk & 3;
  int b = bc >> 5;
  float d0 = dw[b * 2 + 0], d1 = dw[b * 2 + 1];
  const float* p0 = part + (size_t)(bc) * 32768;
  const float* p1 = part + (size_t)(64 + bc) * 32768;
  const float* p2 = part + (size_t)(128 + bc) * 32768;
  const float* al = alpha + (size_t)bc * 32768;
  float* cb = comb + (size_t)bc * 32768;
  float s = 0.f, ss = 0.f;
  int i0 = qt * 8192;
  for (int i = i0 + threadIdx.x; i < i0 + 8192; i += 256) {
    float v = d0 * (p0[i] + p1[i] + p2[i]) + d1 * al[i];
    cb[i] = v;
    s += v; ss += v * v;
  }
  for (int o = 32; o; o >>= 1) {
    s += __shfl_down(s, o);
    ss += __shfl_down(ss, o);
  }
  __shared__ float sb[4], ssb[4];
  int wid = threadIdx.x >> 6, lane = threadIdx.x & 63;
  if (lane == 0) { sb[wid] = s; ssb[wid] = ss; }
  __syncthreads();
  if (threadIdx.x == 0) {
    float S = 0.f, SS = 0.f;
    for (int w = 0; w < 4; ++w) { S += sb[w]; SS += ssb[w]; }
    partial[blk * 2 + 0] = S;
    partial[blk * 2 + 1] = SS;
  }
}

__global__ void finalize_kernel(const float* __restrict__ partial,
                                float* __restrict__ mean, float* __restrict__ rstd) {
  int t = threadIdx.x;  // 64 = bc
  if (t < 64) {
    float S = 0.f, SS = 0.f;
    for (int q = 0; q < 4; ++q) {
      S += partial[(t * 4 + q) * 2 + 0];
      SS += partial[(t * 4 + q) * 2 + 1];
    }
    float m = S * (1.f / 32768.f);
    float var = SS * (1.f / 32768.f) - m * m;
    mean[t] = m;
    rstd[t] = rsqrtf(var + EPS);
  }
}

// ------------------- fused inorm+lrelu+1x1 (32->32), o-split x4 -----------
__global__ __launch_bounds__(256) void last_conv_kernel(
    const float* __restrict__ comb, const float* __restrict__ w,  // [32,32]
    const float* __restrict__ bias,
    const float* __restrict__ meanp, const float* __restrict__ rstdp,
    float* __restrict__ out) {
  int og = blockIdx.x >> 8;
  int chunk = blockIdx.x & 255;
  int vg = chunk * 256 + threadIdx.x;
  int b = vg >> 15, p = vg & 32767;
  float acc[8];
#pragma unroll
  for (int o = 0; o < 8; ++o) acc[o] = 0.f;
  const float* cb = comb + ((size_t)b * 32) * 32768;
  const float* wg = w + (size_t)og * 8 * 32;
  for (int i = 0; i < 32; ++i) {
    float v = cb[(size_t)i * 32768 + p];
    float m = meanp[b * 32 + i], r = rstdp[b * 32 + i];
    v = (v - m) * r;
    v = v >= 0.f ? v : 0.2f * v;
#pragma unroll
    for (int o = 0; o < 8; ++o) acc[o] = fmaf(wg[o * 32 + i], v, acc[o]);
  }
#pragma unroll
  for (int o = 0; o < 8; ++o)
    out[((size_t)b * 32 + og * 8 + o) * 32768 + p] = acc[o] + bias[og * 8 + o];
}

// ---------------------------------------------------------------- launch ---
extern "C" void kernel_launch(void* const* d_in, const int* in_sizes, int n_in,
                              void* d_out, int out_size, void* d_ws, size_t ws_size,
                              hipStream_t stream) {
  (void)in_sizes; (void)n_in; (void)out_size; (void)ws_size;
  const float* x       = (const float*)d_in[0];
  const float* w_first = (const float*)d_in[1];
  const float* b_first = (const float*)d_in[2];
  const float* w_na    = (const float*)d_in[3];
  const float* b_na    = (const float*)d_in[4];
  const float* w_last  = (const float*)d_in[5];
  const float* b_last  = (const float*)d_in[6];
  const float* w_fc1   = (const float*)d_in[7];
  const float* b_fc1   = (const float*)d_in[8];
  const float* w_fc2   = (const float*)d_in[9];
  const float* b_fc2   = (const float*)d_in[10];
  const float* w_off   = (const float*)d_in[11];
  const float* b_off   = (const float*)d_in[12];
  const float* w_def   = (const float*)d_in[13];
  float* out = (float*)d_out;

  float* ws = (float*)d_ws;
  float* mean_x  = ws + 0;        // 128
  float* rstd_x  = ws + 128;      // 128
  float* dwp     = ws + 256;      // 4
  float* mean_f  = ws + 272;      // 64
  float* rstd_f  = ws + 336;      // 64
  float* mean_c  = ws + 400;      // 64
  float* rstd_c  = ws + 464;      // 64
  float* partial = ws + 528;      // 512
  size_t off0 = 2048;
  float* wTd    = ws + off0;                      // 27,648 (slot 28,672)
  float* wT_off = wTd + 28672;                    // 69,984 (slot 71,680)
  float* wT_na  = wT_off + 71680;                 // 27,648 (slot 28,672)
  float* f_cp   = wT_na + 28672;                  // 2,097,152
  float* f_pc   = f_cp + 2097152;                 // (unused slot kept)
  float* offb   = f_pc + 2097152;                 // 5,308,416
  float* alpha  = offb + 5308416;                 // 2,097,152
  float* part   = alpha + 2097152;                // 6,291,456
  float* comb   = part + 6291456;                 // 2,097,152
  // f_norm aliases part: alpha-conv (reads f_norm) completes before
  // deform (writes part) in stream order.
  float* f_norm = part;

  // 1. stats of x (also SE global-avg-pool) + weight transposes
  hipLaunchKernelGGL(stats_kernel, dim3(128), dim3(256), 0, stream, x, mean_x, rstd_x);
  hipLaunchKernelGGL(prep_wdef, dim3(108), dim3(256), 0, stream, w_def, wTd);
  hipLaunchKernelGGL(prep_woff, dim3(274), dim3(256), 0, stream, w_off, wT_off);
  hipLaunchKernelGGL(prep_wna, dim3(108), dim3(256), 0, stream, w_na, wT_na);
  // 2. SE gate -> dw
  hipLaunchKernelGGL(se_kernel, dim3(1), dim3(64), 0, stream,
                     mean_x, w_fc1, b_fc1, w_fc2, b_fc2, dwp);
  // 3. f = conv1x1(lrelu(inorm(x))) (channel-planar only)
  hipLaunchKernelGGL(first_conv_kernel, dim3(1024), dim3(256), 0, stream,
                     x, w_first, b_first, mean_x, rstd_x, f_cp);
  // 4. stats of f, then f_norm = lrelu(inorm(f))
  hipLaunchKernelGGL(stats_kernel, dim3(64), dim3(256), 0, stream, f_cp, mean_f, rstd_f);
  hipLaunchKernelGGL(norm_f_kernel, dim3(2048), dim3(256), 0, stream,
                     f_cp, mean_f, rstd_f, f_norm);
  // 5. off = conv3x3x3(f), zero pad, 32->81 (direct, 2304 blocks)
  hipLaunchKernelGGL((conv3_direct_kernel<9, 81, false>), dim3(2304), dim3(256), 0, stream,
                     f_cp, wT_off, b_off, offb);
  // 6. alpha = conv3x3x3(f_norm), reflect pad (direct, 1024 blocks)
  hipLaunchKernelGGL((conv3_direct_kernel<8, 32, true>), dim3(1024), dim3(256), 0, stream,
                     f_norm, wT_na, b_na, alpha);
  // 7. belta partials (deform), channel-planar gather
  hipLaunchKernelGGL(deform_kernel, dim3(768), dim3(256), 0, stream,
                     f_cp, offb, wTd, part);
  // 8. comb = dw0*belta + dw1*alpha, partial stats
  hipLaunchKernelGGL(combine_kernel, dim3(256), dim3(256), 0, stream,
                     part, alpha, dwp, comb, partial);
  hipLaunchKernelGGL(finalize_kernel, dim3(1), dim3(64), 0, stream,
                     partial, mean_c, rstd_c);
  // 9. out = conv1x1(lrelu(inorm(comb)))
  hipLaunchKernelGGL(last_conv_kernel, dim3(1024), dim3(256), 0, stream,
                     comb, w_last, b_last, mean_c, rstd_c, out);
}

// Round 15
// 518.995 us; speedup vs baseline: 1.3748x; 1.3748x over previous
//
#include <hip/hip_runtime.h>
#include <hip/hip_bf16.h>

#define EPS 1e-5f

__device__ __forceinline__ unsigned short f2bf_rne(float f) {
  unsigned int b = __float_as_uint(f);
  b += 0x7fffu + ((b >> 16) & 1u);
  return (unsigned short)(b >> 16);
}

// ---------------------------------------------------------------- stats ----
__global__ __launch_bounds__(256) void stats_kernel(
    const float* __restrict__ buf, float* __restrict__ mean,
    float* __restrict__ rstd) {
  int bc = blockIdx.x;
  const float* ch = buf + (size_t)bc * 32768;
  float s = 0.f, ss = 0.f;
  for (int i = threadIdx.x; i < 32768; i += 256) {
    float v = ch[i];
    s += v; ss += v * v;
  }
  for (int o = 32; o; o >>= 1) {
    s += __shfl_down(s, o);
    ss += __shfl_down(ss, o);
  }
  __shared__ float sb[4], ssb[4];
  int wid = threadIdx.x >> 6, lane = threadIdx.x & 63;
  if (lane == 0) { sb[wid] = s; ssb[wid] = ss; }
  __syncthreads();
  if (threadIdx.x == 0) {
    float S = 0.f, SS = 0.f;
    for (int w = 0; w < 4; ++w) { S += sb[w]; SS += ssb[w]; }
    float m = S * (1.f / 32768.f);
    float var = SS * (1.f / 32768.f) - m * m;
    mean[bc] = m;
    rstd[bc] = rsqrtf(var + EPS);
  }
}

// ------------------------------------------------------------------- SE ----
__global__ void se_kernel(const float* __restrict__ mean_x,
                          const float* __restrict__ w1, const float* __restrict__ b1,
                          const float* __restrict__ w2, const float* __restrict__ b2,
                          float* __restrict__ dw) {
  __shared__ float hbuf[32];
  int t = threadIdx.x;
  if (t < 32) {
    int b = t >> 4, j = t & 15;
    float a = b1[j];
    for (int c = 0; c < 64; ++c) a += mean_x[b * 64 + c] * w1[j * 64 + c];
    hbuf[t] = a >= 0.f ? a : 0.2f * a;
  }
  __syncthreads();
  if (t < 2) {
    int b = t;
    float l0 = b2[0], l1 = b2[1];
    for (int j = 0; j < 16; ++j) {
      float h = hbuf[b * 16 + j];
      l0 += h * w2[j];
      l1 += h * w2[16 + j];
    }
    float m = fmaxf(l0, l1);
    float e0 = __expf(l0 - m), e1 = __expf(l1 - m);
    float inv = 1.f / (e0 + e1);
    dw[b * 2 + 0] = e0 * inv;
    dw[b * 2 + 1] = e1 * inv;
  }
}

// --------------------------------------------- transpose w_def -> [k][i][o]
__global__ __launch_bounds__(256) void prep_wdef(const float* __restrict__ w_def,
                                                 float* __restrict__ wTd) {
  int idx = blockIdx.x * 256 + threadIdx.x;  // 27*32*32 = 27648
  if (idx < 27648) {
    int o = idx & 31, rest = idx >> 5;
    int i = rest & 31, k = rest >> 5;
    wTd[idx] = w_def[(size_t)(o * 32 + i) * 27 + k];
  }
}

// ------------------------------- transpose w_off [81,32,27] -> [27][32][81]
__global__ __launch_bounds__(256) void prep_woff(const float* __restrict__ w_off,
                                                 float* __restrict__ wT) {
  int idx = blockIdx.x * 256 + threadIdx.x;  // 27*32*81 = 69984
  if (idx < 69984) {
    int o = idx % 81, rest = idx / 81;
    int i = rest & 31, t = rest >> 5;
    wT[idx] = w_off[(size_t)(o * 32 + i) * 27 + t];
  }
}

// -------------------------------- transpose w_na [32,32,27] -> [27][32][32]
__global__ __launch_bounds__(256) void prep_wna(const float* __restrict__ w_na,
                                                float* __restrict__ wT) {
  int idx = blockIdx.x * 256 + threadIdx.x;  // 27*32*32 = 27648
  if (idx < 27648) {
    int o = idx & 31, rest = idx >> 5;
    int i = rest & 31, t = rest >> 5;
    wT[idx] = w_na[(size_t)(o * 32 + i) * 27 + t];
  }
}

// ------------- fused inorm+lrelu+1x1 (64->32), writes f_cp + bf16 [pos][c] -
__global__ __launch_bounds__(256) void first_conv_kernel(
    const float* __restrict__ x, const float* __restrict__ w,   // [32,64]
    const float* __restrict__ bias,
    const float* __restrict__ meanp, const float* __restrict__ rstdp,
    float* __restrict__ f_cp, unsigned short* __restrict__ f_pb) {
  int og = blockIdx.x >> 8;
  int chunk = blockIdx.x & 255;
  int vg = chunk * 256 + threadIdx.x;
  int b = vg >> 15, p = vg & 32767;
  float acc[8];
#pragma unroll
  for (int o = 0; o < 8; ++o) acc[o] = 0.f;
  const float* xb = x + ((size_t)b * 64) * 32768;
  const float* wg = w + (size_t)og * 8 * 64;
  for (int i = 0; i < 64; ++i) {
    float v = xb[(size_t)i * 32768 + p];
    float m = meanp[b * 64 + i], r = rstdp[b * 64 + i];
    v = (v - m) * r;
    v = v >= 0.f ? v : 0.2f * v;
#pragma unroll
    for (int o = 0; o < 8; ++o) acc[o] = fmaf(wg[o * 64 + i], v, acc[o]);
  }
  unsigned short h[8];
#pragma unroll
  for (int o = 0; o < 8; ++o) {
    acc[o] += bias[og * 8 + o];
    f_cp[((size_t)b * 32 + og * 8 + o) * 32768 + p] = acc[o];
    h[o] = f2bf_rne(acc[o]);
  }
  uint4 u;
  u.x = ((unsigned)h[1] << 16) | h[0];
  u.y = ((unsigned)h[3] << 16) | h[2];
  u.z = ((unsigned)h[5] << 16) | h[4];
  u.w = ((unsigned)h[7] << 16) | h[6];
  *(uint4*)(f_pb + ((size_t)b * 32768 + p) * 32 + og * 8) = u;
}

// ------------------------- f_norm = lrelu(inorm(f)) elementwise -----------
__global__ __launch_bounds__(256) void norm_f_kernel(
    const float* __restrict__ f_cp, const float* __restrict__ meanp,
    const float* __restrict__ rstdp, float* __restrict__ f_norm) {
  int i4 = blockIdx.x * 256 + threadIdx.x;   // 524288 float4 groups
  int bc = (i4 * 4) >> 15;
  float m = meanp[bc], r = rstdp[bc];
  float4 v = ((const float4*)f_cp)[i4];
  float4 o;
  o.x = (v.x - m) * r; o.x = o.x >= 0.f ? o.x : 0.2f * o.x;
  o.y = (v.y - m) * r; o.y = o.y >= 0.f ? o.y : 0.2f * o.y;
  o.z = (v.z - m) * r; o.z = o.z >= 0.f ? o.z : 0.2f * o.z;
  o.w = (v.w - m) * r; o.w = o.w >= 0.f ? o.w : 0.2f * o.w;
  ((float4*)f_norm)[i4] = o;
}

// ---------------- implicit-GEMM direct 3x3x3 conv (no LDS, no barriers) ---
template <int OCG, int OCT, bool REFLECT>
__global__ __launch_bounds__(256) void conv3_direct_kernel(
    const float* __restrict__ in,    // [B,32,32768]
    const float* __restrict__ wT,    // [27,32,OCT]
    const float* __restrict__ bias,  // [OCT]
    float* __restrict__ out) {       // [B,OCT,32768]
  int og = blockIdx.x >> 8;
  int chunk = blockIdx.x & 255;
  int vg = chunk * 256 + threadIdx.x;
  int b = vg >> 15, p = vg & 32767;
  int z = p >> 10, y = (p >> 5) & 31, x = p & 31;
  const float* base = in + ((size_t)b * 32) * 32768;

  float acc[OCG];
#pragma unroll
  for (int o = 0; o < OCG; ++o) acc[o] = 0.f;

  for (int t = 0; t < 27; ++t) {
    int dz = t / 9, dy = (t / 3) % 3, dx = t % 3;
    int zz = z + dz - 1, yy = y + dy - 1, xx = x + dx - 1;
    bool valid = true;
    if (REFLECT) {
      zz = zz < 0 ? -zz : (zz > 31 ? 62 - zz : zz);
      yy = yy < 0 ? -yy : (yy > 31 ? 62 - yy : yy);
      xx = xx < 0 ? -xx : (xx > 31 ? 62 - xx : xx);
    } else {
      valid = (unsigned)zz < 32u && (unsigned)yy < 32u && (unsigned)xx < 32u;
      if (!valid) { zz = 0; yy = 0; xx = 0; }
    }
    int off = (zz * 32 + yy) * 32 + xx;
    const float* cptr = base + off;
    const float* wt = wT + (size_t)t * 32 * OCT + og * OCG;  // wave-uniform
#pragma unroll 4
    for (int i = 0; i < 32; ++i) {
      float v = cptr[(size_t)i << 15];
      if (!REFLECT) v = valid ? v : 0.f;
#pragma unroll
      for (int o = 0; o < OCG; ++o)
        acc[o] = fmaf(wt[i * OCT + o], v, acc[o]);
    }
  }
  float* op = out + ((size_t)b * OCT + og * OCG) * 32768 + p;
#pragma unroll
  for (int o = 0; o < OCG; ++o)
    op[(size_t)o * 32768] = acc[o] + bias[og * OCG + o];
}

// --------------------------------------------------------------- deform ----
// v3-bf16: thread-per-position [pos][c] gather (proven best structure) from
// bf16 f_pb -- one position's 32 channels = 64B = 1 cache line (vs 2 fp32),
// halving TA line-touches (the measured bound) and gather instructions
// (4 uint4 loads/corner). Unpack = 2 bitops per element on an 18%-busy VALU.
// Matmul: wave-uniform SGPR weights, i-outer/o-inner (32 indep FMAs).
__global__ __launch_bounds__(256) void deform_kernel(
    const unsigned short* __restrict__ f_pb,  // [B,32768,32] bf16
    const float* __restrict__ offs,  // [B,81,32768]
    const float* __restrict__ wTd,   // [27,32,32] (k,i,o)
    float* __restrict__ part) {      // [3,B,32,32768]
  int bid = blockIdx.x;
  int kg = bid >> 8;                 // 0..2
  int tile = bid & 255;
  int vg = tile * 256 + threadIdx.x;
  int b = vg >> 15, p = vg & 32767;
  int z = p >> 10, y = (p >> 5) & 31, x = p & 31;
  const unsigned short* fb = f_pb + (((size_t)b) << 15) * 32;
  const float* ob = offs + (((size_t)b * 81) << 15);
  int kz = kg - 1;

  float acc[32];
#pragma unroll
  for (int o = 0; o < 32; ++o) acc[o] = 0.f;

  for (int kk = 0; kk < 9; ++kk) {
    int k = kg * 9 + kk;
    int ky = kk / 3 - 1, kx = kk % 3 - 1;

    float oz = ob[(size_t)(k * 3 + 0) * 32768 + p];
    float oy = ob[(size_t)(k * 3 + 1) * 32768 + p];
    float ox = ob[(size_t)(k * 3 + 2) * 32768 + p];
    float pz = (float)(z + kz) + oz;
    float py = (float)(y + ky) + oy;
    float px = (float)(x + kx) + ox;
    float fz = floorf(pz), fy = floorf(py), fxx = floorf(px);
    int iz0 = (int)fz, iy0 = (int)fy, ix0 = (int)fxx;
    float rz = pz - fz, ry = py - fy, rx = px - fxx;

    float v[32];
#pragma unroll
    for (int c = 0; c < 32; ++c) v[c] = 0.f;
#pragma unroll
    for (int corner = 0; corner < 8; ++corner) {
      int dz = corner >> 2, dy = (corner >> 1) & 1, dxx = corner & 1;
      int iz = iz0 + dz, iy = iy0 + dy, ix = ix0 + dxx;
      bool okb = (unsigned)iz < 32u && (unsigned)iy < 32u && (unsigned)ix < 32u;
      float wt = (dz ? rz : 1.f - rz) * (dy ? ry : 1.f - ry) *
                 (dxx ? rx : 1.f - rx);
      if (okb) {
        const uint4* src =
            (const uint4*)(fb + (size_t)((iz * 32 + iy) * 32 + ix) * 32);
        uint4 u0 = src[0], u1 = src[1], u2 = src[2], u3 = src[3];
#define ACCU(U, B0)                                                          \
        v[B0 + 0] = fmaf(wt, __uint_as_float((U).x << 16), v[B0 + 0]);       \
        v[B0 + 1] = fmaf(wt, __uint_as_float((U).x & 0xffff0000u), v[B0 + 1]); \
        v[B0 + 2] = fmaf(wt, __uint_as_float((U).y << 16), v[B0 + 2]);       \
        v[B0 + 3] = fmaf(wt, __uint_as_float((U).y & 0xffff0000u), v[B0 + 3]); \
        v[B0 + 4] = fmaf(wt, __uint_as_float((U).z << 16), v[B0 + 4]);       \
        v[B0 + 5] = fmaf(wt, __uint_as_float((U).z & 0xffff0000u), v[B0 + 5]); \
        v[B0 + 6] = fmaf(wt, __uint_as_float((U).w << 16), v[B0 + 6]);       \
        v[B0 + 7] = fmaf(wt, __uint_as_float((U).w & 0xffff0000u), v[B0 + 7]);
        ACCU(u0, 0) ACCU(u1, 8) ACCU(u2, 16) ACCU(u3, 24)
#undef ACCU
      }
    }
    const float* wk = wTd + (size_t)k * 1024;  // wave-uniform base
#pragma unroll
    for (int i = 0; i < 32; ++i) {
      float vi = v[i];
      const float* wr = wk + i * 32;
#pragma unroll
      for (int o = 0; o < 32; ++o) acc[o] = fmaf(wr[o], vi, acc[o]);
    }
  }
  float* obp = part + (((size_t)kg * 2 + b) * 32) * 32768 + p;
#pragma unroll
  for (int o = 0; o < 32; ++o) obp[(size_t)o * 32768] = acc[o];
}

// ------------------- combine (3 partials + alpha) + partial stats ---------
__global__ __launch_bounds__(256) void combine_kernel(
    const float* __restrict__ part, const float* __restrict__ alpha,
    const float* __restrict__ dw, float* __restrict__ comb,
    float* __restrict__ partial) {   // [256][2]
  int blk = blockIdx.x;              // 64 bc x 4 quarters
  int bc = blk >> 2, qt = blk & 3;
  int b = bc >> 5;
  float d0 = dw[b * 2 + 0], d1 = dw[b * 2 + 1];
  const float* p0 = part + (size_t)(bc) * 32768;
  const float* p1 = part + (size_t)(64 + bc) * 32768;
  const float* p2 = part + (size_t)(128 + bc) * 32768;
  const float* al = alpha + (size_t)bc * 32768;
  float* cb = comb + (size_t)bc * 32768;
  float s = 0.f, ss = 0.f;
  int i0 = qt * 8192;
  for (int i = i0 + threadIdx.x; i < i0 + 8192; i += 256) {
    float v = d0 * (p0[i] + p1[i] + p2[i]) + d1 * al[i];
    cb[i] = v;
    s += v; ss += v * v;
  }
  for (int o = 32; o; o >>= 1) {
    s += __shfl_down(s, o);
    ss += __shfl_down(ss, o);
  }
  __shared__ float sb[4], ssb[4];
  int wid = threadIdx.x >> 6, lane = threadIdx.x & 63;
  if (lane == 0) { sb[wid] = s; ssb[wid] = ss; }
  __syncthreads();
  if (threadIdx.x == 0) {
    float S = 0.f, SS = 0.f;
    for (int w = 0; w < 4; ++w) { S += sb[w]; SS += ssb[w]; }
    partial[blk * 2 + 0] = S;
    partial[blk * 2 + 1] = SS;
  }
}

__global__ void finalize_kernel(const float* __restrict__ partial,
                                float* __restrict__ mean, float* __restrict__ rstd) {
  int t = threadIdx.x;  // 64 = bc
  if (t < 64) {
    float S = 0.f, SS = 0.f;
    for (int q = 0; q < 4; ++q) {
      S += partial[(t * 4 + q) * 2 + 0];
      SS += partial[(t * 4 + q) * 2 + 1];
    }
    float m = S * (1.f / 32768.f);
    float var = SS * (1.f / 32768.f) - m * m;
    mean[t] = m;
    rstd[t] = rsqrtf(var + EPS);
  }
}

// ------------------- fused inorm+lrelu+1x1 (32->32), o-split x4 -----------
__global__ __launch_bounds__(256) void last_conv_kernel(
    const float* __restrict__ comb, const float* __restrict__ w,  // [32,32]
    const float* __restrict__ bias,
    const float* __restrict__ meanp, const float* __restrict__ rstdp,
    float* __restrict__ out) {
  int og = blockIdx.x >> 8;
  int chunk = blockIdx.x & 255;
  int vg = chunk * 256 + threadIdx.x;
  int b = vg >> 15, p = vg & 32767;
  float acc[8];
#pragma unroll
  for (int o = 0; o < 8; ++o) acc[o] = 0.f;
  const float* cb = comb + ((size_t)b * 32) * 32768;
  const float* wg = w + (size_t)og * 8 * 32;
  for (int i = 0; i < 32; ++i) {
    float v = cb[(size_t)i * 32768 + p];
    float m = meanp[b * 32 + i], r = rstdp[b * 32 + i];
    v = (v - m) * r;
    v = v >= 0.f ? v : 0.2f * v;
#pragma unroll
    for (int o = 0; o < 8; ++o) acc[o] = fmaf(wg[o * 32 + i], v, acc[o]);
  }
#pragma unroll
  for (int o = 0; o < 8; ++o)
    out[((size_t)b * 32 + og * 8 + o) * 32768 + p] = acc[o] + bias[og * 8 + o];
}

// ---------------------------------------------------------------- launch ---
extern "C" void kernel_launch(void* const* d_in, const int* in_sizes, int n_in,
                              void* d_out, int out_size, void* d_ws, size_t ws_size,
                              hipStream_t stream) {
  (void)in_sizes; (void)n_in; (void)out_size; (void)ws_size;
  const float* x       = (const float*)d_in[0];
  const float* w_first = (const float*)d_in[1];
  const float* b_first = (const float*)d_in[2];
  const float* w_na    = (const float*)d_in[3];
  const float* b_na    = (const float*)d_in[4];
  const float* w_last  = (const float*)d_in[5];
  const float* b_last  = (const float*)d_in[6];
  const float* w_fc1   = (const float*)d_in[7];
  const float* b_fc1   = (const float*)d_in[8];
  const float* w_fc2   = (const float*)d_in[9];
  const float* b_fc2   = (const float*)d_in[10];
  const float* w_off   = (const float*)d_in[11];
  const float* b_off   = (const float*)d_in[12];
  const float* w_def   = (const float*)d_in[13];
  float* out = (float*)d_out;

  float* ws = (float*)d_ws;
  float* mean_x  = ws + 0;        // 128
  float* rstd_x  = ws + 128;      // 128
  float* dwp     = ws + 256;      // 4
  float* mean_f  = ws + 272;      // 64
  float* rstd_f  = ws + 336;      // 64
  float* mean_c  = ws + 400;      // 64
  float* rstd_c  = ws + 464;      // 64
  float* partial = ws + 528;      // 512
  size_t off0 = 2048;
  float* wTd    = ws + off0;                      // 27,648 (slot 28,672)
  float* wT_off = wTd + 28672;                    // 69,984 (slot 71,680)
  float* wT_na  = wT_off + 71680;                 // 27,648 (slot 28,672)
  float* f_cp   = wT_na + 28672;                  // 2,097,152
  float* f_pc   = f_cp + 2097152;                 // slot reused: bf16 f_pb
  float* offb   = f_pc + 2097152;                 // 5,308,416
  float* alpha  = offb + 5308416;                 // 2,097,152
  float* part   = alpha + 2097152;                // 6,291,456
  float* comb   = part + 6291456;                 // 2,097,152
  unsigned short* f_pb = (unsigned short*)f_pc;   // [B,32768,32] bf16 (4MB)
  // f_norm aliases part: alpha-conv (reads f_norm) completes before
  // deform (writes part) in stream order.
  float* f_norm = part;

  // 1. stats of x (also SE global-avg-pool) + weight transposes
  hipLaunchKernelGGL(stats_kernel, dim3(128), dim3(256), 0, stream, x, mean_x, rstd_x);
  hipLaunchKernelGGL(prep_wdef, dim3(108), dim3(256), 0, stream, w_def, wTd);
  hipLaunchKernelGGL(prep_woff, dim3(274), dim3(256), 0, stream, w_off, wT_off);
  hipLaunchKernelGGL(prep_wna, dim3(108), dim3(256), 0, stream, w_na, wT_na);
  // 2. SE gate -> dw
  hipLaunchKernelGGL(se_kernel, dim3(1), dim3(64), 0, stream,
                     mean_x, w_fc1, b_fc1, w_fc2, b_fc2, dwp);
  // 3. f = conv1x1(lrelu(inorm(x))): f_cp (fp32 planar) + f_pb (bf16 [pos][c])
  hipLaunchKernelGGL(first_conv_kernel, dim3(1024), dim3(256), 0, stream,
                     x, w_first, b_first, mean_x, rstd_x, f_cp, f_pb);
  // 4. stats of f, then f_norm = lrelu(inorm(f))
  hipLaunchKernelGGL(stats_kernel, dim3(64), dim3(256), 0, stream, f_cp, mean_f, rstd_f);
  hipLaunchKernelGGL(norm_f_kernel, dim3(2048), dim3(256), 0, stream,
                     f_cp, mean_f, rstd_f, f_norm);
  // 5. off = conv3x3x3(f), zero pad, 32->81 (direct, 2304 blocks)
  hipLaunchKernelGGL((conv3_direct_kernel<9, 81, false>), dim3(2304), dim3(256), 0, stream,
                     f_cp, wT_off, b_off, offb);
  // 6. alpha = conv3x3x3(f_norm), reflect pad (direct, 1024 blocks)
  hipLaunchKernelGGL((conv3_direct_kernel<8, 32, true>), dim3(1024), dim3(256), 0, stream,
                     f_norm, wT_na, b_na, alpha);
  // 7. belta partials (deform), bf16 [pos][c] gather
  hipLaunchKernelGGL(deform_kernel, dim3(768), dim3(256), 0, stream,
                     f_pb, offb, wTd, part);
  // 8. comb = dw0*belta + dw1*alpha, partial stats
  hipLaunchKernelGGL(combine_kernel, dim3(256), dim3(256), 0, stream,
                     part, alpha, dwp, comb, partial);
  hipLaunchKernelGGL(finalize_kernel, dim3(1), dim3(64), 0, stream,
                     partial, mean_c, rstd_c);
  // 9. out = conv1x1(lrelu(inorm(comb)))
  hipLaunchKernelGGL(last_conv_kernel, dim3(1024), dim3(256), 0, stream,
                     comb, w_last, b_last, mean_c, rstd_c, out);
}